// Round 8
// baseline (218.701 us; speedup 1.0000x reference)
//
#include <hip/hip_runtime.h>
#include <hip/hip_bf16.h>

// SpanPairPairedLayer: B=8, S=1024, D=1024, P=4096, DR=512, DO=512
// GEMM1 (MODE 1): span fp32 [8192][1024] @ W1T -> C1 bf16 [8192][512]; BM=128 BN=64, grid(8,64)
// GEMM2 (MODE 2): gathered C1 rows [32768][1024] @ WrT -> out fp32;    BM=128 BN=128, grid(256,4)
//
// LDS tiles are stored chunk-major-within-16-row-stripes:
//   byte_off(row, k-chunk) = (row>>4)*1024 + (kchunk)*256 + (row&15)*16
// Staged so global_load_lds' linear dest (wave base + lane*16) realizes this layout:
//   lane l stages (row = stripe*16 + (l&15), kchunk = l>>4).
// Fragment reads (lane: fr=lane&15, kchunk=lane>>4) are then 16 consecutive
// 16B slots per quarter-wave -> conflict-free ds_read_b128.

#define BK 32

typedef __attribute__((ext_vector_type(8))) short s8v;    // 8 bf16
typedef __attribute__((ext_vector_type(4))) float f4v;

__device__ __forceinline__ unsigned short f2bf(float f) {
    unsigned int u = __float_as_uint(f);
    u += 0x7fffu + ((u >> 16) & 1u);   // RNE
    return (unsigned short)(u >> 16);
}

__device__ __forceinline__ void gload16(const void* g, void* l) {
    __builtin_amdgcn_global_load_lds(
        (const __attribute__((address_space(1))) void*)g,
        (__attribute__((address_space(3))) void*)l, 16, 0, 0);
}

// ---- prep: W [1024][512] fp32 -> WT [512][1024] bf16 ----
__global__ void transpose_w_k(const float* __restrict__ in, unsigned short* __restrict__ out) {
    __shared__ float tile[32][33];
    int k0 = blockIdx.x * 32, n0 = blockIdx.y * 32;
    int tx = threadIdx.x, ty = threadIdx.y;
    tile[ty][tx] = in[(size_t)(k0 + ty) * 512 + n0 + tx];
    __syncthreads();
    out[(size_t)(n0 + ty) * 1024 + k0 + tx] = f2bf(tile[tx][ty]);
}

template <int MODE>
__global__ __launch_bounds__(256)
void gemm_tile(const void* __restrict__ Ap,               // MODE1: span fp32; MODE2: C1 bf16 [8192][512]
               const unsigned short* __restrict__ BT,     // [512][1024] bf16 (N-major)
               const float* __restrict__ bias,            // [512]
               const int* __restrict__ pairs,             // [B*P*2] int32 (MODE2)
               void* __restrict__ outp) {
    constexpr int BN = (MODE == 1) ? 64 : 128;
    constexpr int NF = BN / 32;                 // n-fragments per wave (wave cols = BN/2)
    __shared__ unsigned short Asm[128 * BK];    // 8 stripes x 1KB
    __shared__ unsigned short Bsm[BN * BK];     // BN/16 stripes

    const int t = threadIdx.x;
    const int lane = t & 63;
    const int w = t >> 6;                       // wave 0..3
    const int wr = w >> 1, wc = w & 1;          // 2x2 wave grid
    const int bm0 = (MODE == 1 ? (int)blockIdx.y : (int)blockIdx.x) * 128;
    const int bn0 = (MODE == 1 ? (int)blockIdx.x : (int)blockIdx.y) * BN;

    const int sl = lane & 15;                   // row within stripe (stage & read)
    const int sc = lane >> 4;                   // k-chunk 0..3   (stage & read)

    // ---- staging source addresses ----
    const float* aF0 = nullptr; const float* aF1 = nullptr;                 // MODE1
    const unsigned short *aP0=nullptr,*aP1=nullptr,*aC0=nullptr,*aC1=nullptr; // MODE2
    if constexpr (MODE == 1) {
        aF0 = (const float*)Ap + (size_t)(bm0 + w * 16 + sl) * 1024 + sc * 8;
        aF1 = aF0 + (size_t)64 * 1024;
    } else {
        int g0 = bm0 + w * 16 + sl, g1 = g0 + 64;
        int b0 = g0 >> 12, b1 = g1 >> 12;       // 4096 pairs per batch
        int ip0 = pairs[g0 * 2 + 0], ic0 = pairs[g0 * 2 + 1];
        int ip1 = pairs[g1 * 2 + 0], ic1 = pairs[g1 * 2 + 1];
        const unsigned short* C1b = (const unsigned short*)Ap;
        aP0 = C1b + (size_t)(b0 * 1024 + ip0) * 512 + sc * 8;   // parent: k<512
        aC0 = C1b + (size_t)(b0 * 1024 + ic0) * 512 + sc * 8;   // child:  k>=512
        aP1 = C1b + (size_t)(b1 * 1024 + ip1) * 512 + sc * 8;
        aC1 = C1b + (size_t)(b1 * 1024 + ic1) * 512 + sc * 8;
    }
    const unsigned short* bS0 = BT + (size_t)(bn0 + w * 16 + sl) * 1024 + sc * 8;
    const unsigned short* bS1 = BT + (size_t)(bn0 + 64 + w * 16 + sl) * 1024 + sc * 8; // MODE2 only

    // wave-uniform LDS bases (lane lands at +lane*16B = +lane*8 shorts)
    unsigned short* aL0 = Asm + w * 512;
    unsigned short* aL1 = Asm + (4 + w) * 512;
    unsigned short* bL0 = Bsm + w * 512;
    unsigned short* bL1 = Bsm + (4 + w) * 512;

    f4v acc[4][NF] = {};

    for (int k0 = 0; k0 < 1024; k0 += BK) {
        __syncthreads();                        // prev iter's ds_reads done
        if constexpr (MODE == 1) {
            f4v u0 = *(const f4v*)(aF0 + k0);
            f4v u1 = *(const f4v*)(aF0 + k0 + 4);
            f4v u2 = *(const f4v*)(aF1 + k0);
            f4v u3 = *(const f4v*)(aF1 + k0 + 4);
            gload16(bS0 + k0, bL0);
            s8v o0, o1;
#pragma unroll
            for (int j = 0; j < 4; ++j) {
                o0[j] = (short)f2bf(u0[j]); o0[4 + j] = (short)f2bf(u1[j]);
                o1[j] = (short)f2bf(u2[j]); o1[4 + j] = (short)f2bf(u3[j]);
            }
            *(s8v*)(aL0 + lane * 8) = o0;       // linear per-lane write: conflict-free
            *(s8v*)(aL1 + lane * 8) = o1;
        } else {
            const unsigned short *s0, *s1; int ka;
            if (k0 < 512) { s0 = aP0; s1 = aP1; ka = k0; }
            else          { s0 = aC0; s1 = aC1; ka = k0 - 512; }
            gload16(s0 + ka, aL0);
            gload16(s1 + ka, aL1);
            gload16(bS0 + k0, bL0);
            gload16(bS1 + k0, bL1);
        }
        __syncthreads();                        // drains vmcnt+lgkmcnt

        s8v af[4], bb[NF];
#pragma unroll
        for (int m = 0; m < 4; ++m)             // A stripe = wr*4+m
            af[m] = *(const s8v*)&Asm[(wr * 4 + m) * 512 + sc * 128 + sl * 8];
#pragma unroll
        for (int n = 0; n < NF; ++n)            // B stripe = wc*NF+n
            bb[n] = *(const s8v*)&Bsm[(wc * NF + n) * 512 + sc * 128 + sl * 8];
#pragma unroll
        for (int m = 0; m < 4; ++m)
#pragma unroll
            for (int n = 0; n < NF; ++n)
                acc[m][n] = __builtin_amdgcn_mfma_f32_16x16x32_bf16(af[m], bb[n], acc[m][n], 0, 0, 0);
    }

    // epilogue: C/D layout col=lane&15, row=(lane>>4)*4+reg
    const int orow0 = bm0 + wr * 64 + sc * 4;
    const int ocol0 = bn0 + wc * (BN / 2) + sl;
#pragma unroll
    for (int m = 0; m < 4; ++m) {
#pragma unroll
        for (int n = 0; n < NF; ++n) {
            int col = ocol0 + n * 16;
            float bv = bias[col];
#pragma unroll
            for (int r = 0; r < 4; ++r) {
                int row = orow0 + m * 16 + r;
                float v = fmaxf(acc[m][n][r] + bv, 0.0f);
                if constexpr (MODE == 1)
                    ((unsigned short*)outp)[(size_t)row * 512 + col] = f2bf(v);
                else
                    ((float*)outp)[(size_t)row * 512 + col] = v;
            }
        }
    }
}

extern "C" void kernel_launch(void* const* d_in, const int* in_sizes, int n_in,
                              void* d_out, int out_size, void* d_ws, size_t ws_size,
                              hipStream_t stream) {
    const float* span  = (const float*)d_in[0];
    const int*   pairs = (const int*)d_in[1];    // int32 (JAX x64 disabled)
    const float* W1    = (const float*)d_in[2];
    const float* b1    = (const float*)d_in[3];
    const float* Wr    = (const float*)d_in[4];
    const float* br    = (const float*)d_in[5];
    float*       out   = (float*)d_out;

    // ws: W1T 1MB | WrT 1MB | C1 8MB
    char* ws = (char*)d_ws;
    unsigned short* W1T = (unsigned short*)ws;
    unsigned short* WrT = (unsigned short*)(ws + 1048576);
    unsigned short* C1  = (unsigned short*)(ws + 2097152);

    transpose_w_k<<<dim3(32, 16), dim3(32, 32), 0, stream>>>(W1, W1T);
    transpose_w_k<<<dim3(32, 16), dim3(32, 32), 0, stream>>>(Wr, WrT);

    gemm_tile<1><<<dim3(8, 64),  256, 0, stream>>>(span, W1T, b1, nullptr, C1);
    gemm_tile<2><<<dim3(256, 4), 256, 0, stream>>>(C1,   WrT, br, pairs,   out);
}

// Round 10
// 187.003 us; speedup vs baseline: 1.1695x; 1.1695x over previous
//
#include <hip/hip_runtime.h>
#include <hip/hip_bf16.h>

// SpanPairPairedLayer: B=8, S=1024, D=1024, P=4096, DR=512, DO=512
// gemm_span (MODE 1): span fp32 [8192][1024] @ W1T -> C1 bf16 [8192][512]; BM=128 BN=64, grid(8,64)
// gemm_pair (MODE 2): gathered C1 rows [32768][1024] @ WrT -> out fp32;    BM=128 BN=128, grid(256,4)
//
// LDS tile layout (per 16-row stripe of 1KB): row r at r*64B, 4 chunk-slots of 16B.
// Swizzle: slot(r, c) = c ^ ((r>>2)&3)  -- permutes chunks WITHIN each row's 64B.
//  - staging: lane l writes linear l*16B (= row l>>2, slot l&3), so it fetches
//    logical chunk (l&3)^((l>>4)&3). 4 lanes/row still cover one aligned 64B
//    segment -> global coalescing identical to the fast R3 kernel.
//  - fragment read: row fr, logical chunk fc at byte fr*64 + (fc^(fr>>2))*16
//    -> 16 lanes spread over 8 four-bank groups = 2 lanes/bank = conflict-free.

#define BK 32

typedef __attribute__((ext_vector_type(8))) short s8v;    // 8 bf16
typedef __attribute__((ext_vector_type(4))) float f4v;

__device__ __forceinline__ unsigned short f2bf(float f) {
    unsigned int u = __float_as_uint(f);
    u += 0x7fffu + ((u >> 16) & 1u);   // RNE
    return (unsigned short)(u >> 16);
}

__device__ __forceinline__ void gload16(const void* g, void* l) {
    __builtin_amdgcn_global_load_lds(
        (const __attribute__((address_space(1))) void*)g,
        (__attribute__((address_space(3))) void*)l, 16, 0, 0);
}

// ---- prep: W [1024][512] fp32 -> WT [512][1024] bf16 ----
__global__ void transpose_w_k(const float* __restrict__ in, unsigned short* __restrict__ out) {
    __shared__ float tile[32][33];
    int k0 = blockIdx.x * 32, n0 = blockIdx.y * 32;
    int tx = threadIdx.x, ty = threadIdx.y;
    tile[ty][tx] = in[(size_t)(k0 + ty) * 512 + n0 + tx];
    __syncthreads();
    out[(size_t)(n0 + ty) * 1024 + k0 + tx] = f2bf(tile[tx][ty]);
}

template <int MODE>
__device__ __forceinline__ void gemm_body(unsigned short* Asm, unsigned short* Bsm,
                                          const void* __restrict__ Ap,
                                          const unsigned short* __restrict__ BT,
                                          const float* __restrict__ bias,
                                          const int* __restrict__ pairs,
                                          void* __restrict__ outp) {
    constexpr int BN = (MODE == 1) ? 64 : 128;
    constexpr int NF = BN / 32;
    const int t = threadIdx.x;
    const int lane = t & 63;
    const int w = t >> 6;                       // wave 0..3
    const int wr = w >> 1, wc = w & 1;          // 2x2 wave grid
    const int bm0 = (MODE == 1 ? (int)blockIdx.y : (int)blockIdx.x) * 128;
    const int bn0 = (MODE == 1 ? (int)blockIdx.x : (int)blockIdx.y) * BN;

    // staging: lane l -> (row = l>>2, slot = l&3); fetch logical chunk slot^((row>>2)&3)
    const int srow = lane >> 2;                               // row within stripe
    const int sk = ((lane & 3) ^ ((lane >> 4) & 3)) * 8;      // logical k-elem offset

    const float* aF0 = nullptr; const float* aF1 = nullptr;
    const unsigned short *aP0=nullptr,*aP1=nullptr,*aC0=nullptr,*aC1=nullptr;
    if constexpr (MODE == 1) {
        aF0 = (const float*)Ap + (size_t)(bm0 + w * 16 + srow) * 1024 + sk;
        aF1 = aF0 + (size_t)64 * 1024;
    } else {
        int g0 = bm0 + w * 16 + srow, g1 = g0 + 64;
        int b0 = g0 >> 12, b1 = g1 >> 12;       // 4096 pairs per batch
        int ip0 = pairs[g0 * 2 + 0], ic0 = pairs[g0 * 2 + 1];
        int ip1 = pairs[g1 * 2 + 0], ic1 = pairs[g1 * 2 + 1];
        const unsigned short* C1b = (const unsigned short*)Ap;
        aP0 = C1b + (size_t)(b0 * 1024 + ip0) * 512 + sk;     // parent: k<512
        aC0 = C1b + (size_t)(b0 * 1024 + ic0) * 512 + sk;     // child:  k>=512
        aP1 = C1b + (size_t)(b1 * 1024 + ip1) * 512 + sk;
        aC1 = C1b + (size_t)(b1 * 1024 + ic1) * 512 + sk;
    }
    const unsigned short* bS0 = BT + (size_t)(bn0 + w * 16 + srow) * 1024 + sk;
    const unsigned short* bS1 = BT + (size_t)(bn0 + 64 + w * 16 + srow) * 1024 + sk;

    // wave-uniform LDS bases (lane lands at +lane*16B)
    unsigned short* aL0 = Asm + w * 512;
    unsigned short* aL1 = Asm + (4 + w) * 512;
    unsigned short* bL0 = Bsm + w * 512;
    unsigned short* bL1 = Bsm + (4 + w) * 512;  // MODE2 only

    f4v acc[4][NF] = {};

    const int fr = lane & 15;                   // fragment row (A) / col (B)
    const int fc = lane >> 4;                   // logical k-chunk 0..3
    const int rdoff = fr * 32 + ((fc ^ (fr >> 2)) * 8);   // swizzled read offset (shorts)

    for (int k0 = 0; k0 < 1024; k0 += BK) {
        __syncthreads();                        // prev iter's ds_reads done
        if constexpr (MODE == 1) {
            f4v u0 = *(const f4v*)(aF0 + k0);
            f4v u1 = *(const f4v*)(aF0 + k0 + 4);
            f4v u2 = *(const f4v*)(aF1 + k0);
            f4v u3 = *(const f4v*)(aF1 + k0 + 4);
            gload16(bS0 + k0, bL0);
            s8v o0, o1;
#pragma unroll
            for (int j = 0; j < 4; ++j) {
                o0[j] = (short)f2bf(u0[j]); o0[4 + j] = (short)f2bf(u1[j]);
                o1[j] = (short)f2bf(u2[j]); o1[4 + j] = (short)f2bf(u3[j]);
            }
            *(s8v*)(aL0 + lane * 8) = o0;       // linear 16B/lane: conflict-free
            *(s8v*)(aL1 + lane * 8) = o1;
        } else {
            const unsigned short *s0, *s1; int ka;
            if (k0 < 512) { s0 = aP0; s1 = aP1; ka = k0; }
            else          { s0 = aC0; s1 = aC1; ka = k0 - 512; }
            gload16(s0 + ka, aL0);
            gload16(s1 + ka, aL1);
            gload16(bS0 + k0, bL0);
            gload16(bS1 + k0, bL1);
        }
        __syncthreads();                        // drains vmcnt+lgkmcnt

        s8v af[4], bb[NF];
#pragma unroll
        for (int m = 0; m < 4; ++m)             // A stripe = wr*4+m
            af[m] = *(const s8v*)&Asm[(wr * 4 + m) * 512 + rdoff];
#pragma unroll
        for (int n = 0; n < NF; ++n)            // B stripe = wc*NF+n
            bb[n] = *(const s8v*)&Bsm[(wc * NF + n) * 512 + rdoff];
#pragma unroll
        for (int m = 0; m < 4; ++m)
#pragma unroll
            for (int n = 0; n < NF; ++n)
                acc[m][n] = __builtin_amdgcn_mfma_f32_16x16x32_bf16(af[m], bb[n], acc[m][n], 0, 0, 0);
    }

    // epilogue: C/D layout col=lane&15, row=(lane>>4)*4+reg
    const int orow0 = bm0 + wr * 64 + fc * 4;
    const int ocol0 = bn0 + wc * (BN / 2) + fr;
#pragma unroll
    for (int m = 0; m < 4; ++m) {
#pragma unroll
        for (int n = 0; n < NF; ++n) {
            int col = ocol0 + n * 16;
            float bv = bias[col];
#pragma unroll
            for (int r = 0; r < 4; ++r) {
                int row = orow0 + m * 16 + r;
                float v = fmaxf(acc[m][n][r] + bv, 0.0f);
                if constexpr (MODE == 1)
                    ((unsigned short*)outp)[(size_t)row * 512 + col] = f2bf(v);
                else
                    ((float*)outp)[(size_t)row * 512 + col] = v;
            }
        }
    }
}

__global__ __launch_bounds__(256)
void gemm_span(const float* __restrict__ A, const unsigned short* __restrict__ BT,
               const float* __restrict__ bias, unsigned short* __restrict__ C1) {
    __shared__ unsigned short Asm[128 * BK];
    __shared__ unsigned short Bsm[64 * BK];
    gemm_body<1>(Asm, Bsm, A, BT, bias, nullptr, C1);
}

__global__ __launch_bounds__(256)
void gemm_pair(const unsigned short* __restrict__ C1, const unsigned short* __restrict__ BT,
               const float* __restrict__ bias, const int* __restrict__ pairs,
               float* __restrict__ out) {
    __shared__ unsigned short Asm[128 * BK];
    __shared__ unsigned short Bsm[128 * BK];
    gemm_body<2>(Asm, Bsm, C1, BT, bias, pairs, out);
}

extern "C" void kernel_launch(void* const* d_in, const int* in_sizes, int n_in,
                              void* d_out, int out_size, void* d_ws, size_t ws_size,
                              hipStream_t stream) {
    const float* span  = (const float*)d_in[0];
    const int*   pairs = (const int*)d_in[1];    // int32 (JAX x64 disabled)
    const float* W1    = (const float*)d_in[2];
    const float* b1    = (const float*)d_in[3];
    const float* Wr    = (const float*)d_in[4];
    const float* br    = (const float*)d_in[5];
    float*       out   = (float*)d_out;

    // ws: W1T 1MB | WrT 1MB | C1 8MB
    char* ws = (char*)d_ws;
    unsigned short* W1T = (unsigned short*)ws;
    unsigned short* WrT = (unsigned short*)(ws + 1048576);
    unsigned short* C1  = (unsigned short*)(ws + 2097152);

    transpose_w_k<<<dim3(32, 16), dim3(32, 32), 0, stream>>>(W1, W1T);
    transpose_w_k<<<dim3(32, 16), dim3(32, 32), 0, stream>>>(Wr, WrT);

    gemm_span<<<dim3(8, 64),  256, 0, stream>>>(span, W1T, b1, C1);
    gemm_pair<<<dim3(256, 4), 256, 0, stream>>>(C1, WrT, br, pairs, out);
}